// Round 2
// baseline (840.494 us; speedup 1.0000x reference)
//
#include <hip/hip_runtime.h>

#define TOK   32768
#define DM    768
#define KDIM  768
#define LSEQ  4096
#define NC    32
#define CL    128
#define NCHAIN 6144

typedef __bf16 bf16x8 __attribute__((ext_vector_type(8)));
typedef float  f32x4  __attribute__((ext_vector_type(4)));
typedef unsigned short u16;

__device__ __forceinline__ u16 f2bf(float f) {
  unsigned u = __builtin_bit_cast(unsigned, f);
  u += 0x7fffu + ((u >> 16) & 1u);
  return (u16)(u >> 16);
}
__device__ __forceinline__ float bf2f(u16 h) {
  unsigned u = ((unsigned)h) << 16;
  return __builtin_bit_cast(float, u);
}

#define GLOAD_LDS16(g, l) __builtin_amdgcn_global_load_lds( \
    (const __attribute__((address_space(1))) void*)(g),     \
    (__attribute__((address_space(3))) void*)(l), 16, 0, 0)

// ---------------- fp32 -> bf16 weight convert ----------------
__global__ void cvt_k(const float* __restrict__ src, u16* __restrict__ dst, int n) {
  int i = blockIdx.x * 256 + threadIdx.x;
  if (i < n) dst[i] = f2bf(src[i]);
}

// ---------------- W_dt = dt_proj_w (768x48) @ x_proj_w[:48] (48x768) -> bf16 ----------------
__global__ __launch_bounds__(256)
void wdt_k(const float* __restrict__ dtw, const float* __restrict__ xw,
           u16* __restrict__ W) {
  int i = blockIdx.x;       // output row 0..767
  int j = threadIdx.x;      // cols j, j+256, j+512
  float a0 = 0.f, a1 = 0.f, a2 = 0.f;
  for (int r = 0; r < 48; ++r) {
    float d = dtw[i * 48 + r];
    const float* xr = xw + r * DM;
    a0 += d * xr[j];
    a1 += d * xr[j + 256];
    a2 += d * xr[j + 512];
  }
  W[i * DM + j]       = f2bf(a0);
  W[i * DM + j + 256] = f2bf(a1);
  W[i * DM + j + 512] = f2bf(a2);
}

// ---------------- RMSNorm: x (fp32) -> xn (bf16) ----------------
__global__ __launch_bounds__(256)
void rmsnorm_k(const float* __restrict__ x, const float* __restrict__ w,
               u16* __restrict__ xnb) {
  long t = blockIdx.x;
  const float* xr = x + t * DM;
  int tid = threadIdx.x;
  float v0 = xr[tid], v1 = xr[tid + 256], v2 = xr[tid + 512];
  float s = v0 * v0 + v1 * v1 + v2 * v2;
#pragma unroll
  for (int o = 32; o; o >>= 1) s += __shfl_down(s, o, 64);
  __shared__ float red[4];
  if ((tid & 63) == 0) red[tid >> 6] = s;
  __syncthreads();
  float tot = red[0] + red[1] + red[2] + red[3];
  float sc = rsqrtf(tot * (1.f / 768.f) + 1e-6f);
  xnb[t * DM + tid]       = f2bf(v0 * sc * w[tid]);
  xnb[t * DM + tid + 256] = f2bf(v1 * sc * w[tid + 256]);
  xnb[t * DM + tid + 512] = f2bf(v2 * sc * w[tid + 512]);
}

// ---------------- 256x256 MFMA GEMM, BK=32, 8 waves, 3-buffer LDS, counted vmcnt ----
// C[m][n] = sum_k A[m][k]*B[n][k]; A,B bf16 row-major stride KDIM. K = KDIM = 768.
// LDS swizzle: within a 64B row, 16B slot_phys = slot_logical ^ ((row>>1)&3),
// applied on the global source address (gload_lds writes linearly) and on ds_read.
// EPI: 0 plain fp32; 1 in_proj (conv+silu -> o0, silu(z) -> o1); 2 bias+softplus -> C.
template <int EPI>
__global__ __launch_bounds__(512, 2)
void gemm256(const u16* __restrict__ A, const u16* __restrict__ B,
             float* __restrict__ C,
             const float* __restrict__ w0, const float* __restrict__ w1,
             u16* __restrict__ o0, u16* __restrict__ o1) {
  __shared__ __align__(16) u16 sm[49152];  // 3 bufs x (A 16KB + B 16KB)
  const int tid  = threadIdx.x;
  const int lane = tid & 63;
  const int wid  = tid >> 6;   // 0..7
  const int wm   = wid >> 2;   // 0..1
  const int wn   = wid & 3;    // 0..3
  const long rowBase = (long)blockIdx.y * 256;
  const long colBase = (long)blockIdx.x * 256;

  // staging: per tile 16 chunks of 1024B per matrix; wave wid owns chunks wid*2, wid*2+1.
  // chunk = 16 rows x 64B. lane l -> row_in = l>>2, phys slot = l&3,
  // logical slot = (l&3) ^ ((l>>3)&3)  (since (row>>1)&3 == (l>>3)&3 within a chunk)
  const int rin   = lane >> 2;
  const int slotl = (lane & 3) ^ ((lane >> 3) & 3);
  const int ca0   = wid * 2;

  const u16* gA0 = A + (rowBase + ca0 * 16 + rin) * KDIM + slotl * 8;
  const u16* gA1 = gA0 + 16 * KDIM;
  const u16* gB0 = B + (colBase + ca0 * 16 + rin) * KDIM + slotl * 8;
  const u16* gB1 = gB0 + 16 * KDIM;

  char* const smc = (char*)sm;
  const int ldsC = ca0 * 1024;

  // ds_read addressing (per lane, constant over fa/fb/T):
  const int l15  = lane & 15;
  const int hi   = lane >> 4;
  const int xorv = (l15 >> 1) & 3;
  const int aOff = (wm * 128 + l15) * 64 + ((hi ^ xorv) * 16);
  const int bOff = 16384 + (wn * 64 + l15) * 64 + ((hi ^ xorv) * 16);

  f32x4 acc[8][4] = {};
  constexpr int NT = KDIM / 32;  // 24

  auto STAGE = [&](int t) {
    char* bb = smc + (t % 3) * 32768;
    long ko = (long)t * 32;
    GLOAD_LDS16(gA0 + ko, bb + ldsC);
    GLOAD_LDS16(gA1 + ko, bb + ldsC + 1024);
    GLOAD_LDS16(gB0 + ko, bb + 16384 + ldsC);
    GLOAD_LDS16(gB1 + ko, bb + 16384 + ldsC + 1024);
  };

  STAGE(0);
  STAGE(1);
  asm volatile("s_waitcnt vmcnt(4)" ::: "memory");   // tile 0 landed; tile 1 in flight
  __builtin_amdgcn_s_barrier();
  __builtin_amdgcn_sched_barrier(0);

  for (int T = 0; T < NT; ++T) {
    char* bb = smc + (T % 3) * 32768;
    bf16x8 av[8], bv[4];
#pragma unroll
    for (int fa = 0; fa < 8; ++fa)
      av[fa] = *(const bf16x8*)(bb + aOff + fa * 1024);
#pragma unroll
    for (int fb = 0; fb < 4; ++fb)
      bv[fb] = *(const bf16x8*)(bb + bOff + fb * 1024);
    if (T + 2 < NT) STAGE(T + 2);   // overwrites buf holding tile T-1 (fully consumed)
    __builtin_amdgcn_s_setprio(1);
#pragma unroll
    for (int fa = 0; fa < 8; ++fa)
#pragma unroll
      for (int fb = 0; fb < 4; ++fb)
        acc[fa][fb] = __builtin_amdgcn_mfma_f32_16x16x32_bf16(av[fa], bv[fb], acc[fa][fb], 0, 0, 0);
    __builtin_amdgcn_s_setprio(0);
    if (T < NT - 1) {
      if (T + 2 < NT) asm volatile("s_waitcnt vmcnt(4)" ::: "memory");  // tile T+1 landed
      else            asm volatile("s_waitcnt vmcnt(0)" ::: "memory");  // tail drain
      __builtin_amdgcn_s_barrier();
      __builtin_amdgcn_sched_barrier(0);
    }
  }

#pragma unroll
  for (int fa = 0; fa < 8; ++fa)
#pragma unroll
    for (int fb = 0; fb < 4; ++fb)
#pragma unroll
      for (int j = 0; j < 4; ++j) {
        long grow = rowBase + wm * 128 + fa * 16 + hi * 4 + j;
        long gcol = colBase + wn * 64 + fb * 16 + l15;
        float v = acc[fa][fb][j];
        if (EPI == 0) {
          C[grow * DM + gcol] = v;
        } else if (EPI == 1) {
          if (gcol < DM) {
            float t = v * w0[gcol] + w1[gcol];
            o0[grow * DM + gcol] = f2bf(t / (1.f + __expf(-t)));
          } else {
            o1[grow * DM + (gcol - DM)] = f2bf(v / (1.f + __expf(-v)));
          }
        } else {
          float t = v + w0[gcol];
          float d = (t > 20.f) ? t : log1pf(__expf(t));
          C[grow * DM + gcol] = d;
        }
      }
}

// ---------------- Bm/C: dots of xc with x_proj_w rows 48,49 (fp32 weights) ----------------
__global__ __launch_bounds__(256)
void bmc_k(const u16* __restrict__ xcb, const float* __restrict__ xw,
           float* __restrict__ bmc) {
  int lane = threadIdx.x & 63, wid = threadIdx.x >> 6;
  long t = (long)blockIdx.x * 4 + wid;
  const u16* xr = xcb + t * DM;
  const float* w48 = xw + 48 * DM;
  const float* w49 = xw + 49 * DM;
  float s0 = 0.f, s1 = 0.f;
#pragma unroll
  for (int i = 0; i < 3; ++i) {
    int e = i * 256 + lane * 4;
    ushort4 xv = *(const ushort4*)&xr[e];
    float4 a = *(const float4*)&w48[e];
    float4 b = *(const float4*)&w49[e];
    float x0 = bf2f(xv.x), x1 = bf2f(xv.y), x2 = bf2f(xv.z), x3 = bf2f(xv.w);
    s0 += x0 * a.x + x1 * a.y + x2 * a.z + x3 * a.w;
    s1 += x0 * b.x + x1 * b.y + x2 * b.z + x3 * b.w;
  }
#pragma unroll
  for (int o = 32; o; o >>= 1) { s0 += __shfl_down(s0, o, 64); s1 += __shfl_down(s1, o, 64); }
  if (lane == 0) { bmc[t * 2] = s0; bmc[t * 2 + 1] = s1; }
}

// ---------------- selective scan (N_STATE=1), chunked 3-pass ----------------
__global__ __launch_bounds__(256)
void scan1_k(const float* __restrict__ delta, const u16* __restrict__ xcb,
             const float* __restrict__ bmc, const float* __restrict__ A_log,
             float* __restrict__ aprod, float* __restrict__ hend) {
  int e = blockIdx.x * 256 + threadIdx.x;
  int b = blockIdx.y;
  int c = blockIdx.z;
  float Ae = -__expf(A_log[e]);
  float ap = 1.f, h = 0.f;
  long base = (long)b * LSEQ + (long)c * CL;
  for (int i = 0; i < CL; ++i) {
    long t = base + i;
    float d = delta[t * DM + e];
    float xc = bf2f(xcb[t * DM + e]);
    float Bm = bmc[t * 2];
    float a = __expf(d * Ae);
    ap *= a;
    h = a * h + d * Bm * xc;
  }
  int chain = b * DM + e;
  aprod[c * NCHAIN + chain] = ap;
  hend[c * NCHAIN + chain] = h;
}

__global__ __launch_bounds__(256)
void scan2_k(const float* __restrict__ aprod, const float* __restrict__ hend,
             float* __restrict__ carry) {
  int chain = blockIdx.x * 256 + threadIdx.x;
  float h = 0.f;
  for (int c = 0; c < NC; ++c) {
    carry[c * NCHAIN + chain] = h;
    h = aprod[c * NCHAIN + chain] * h + hend[c * NCHAIN + chain];
  }
}

__global__ __launch_bounds__(256)
void scan3_k(const float* __restrict__ delta, const u16* __restrict__ xcb,
             const float* __restrict__ bmc, const float* __restrict__ A_log,
             const float* __restrict__ Dp, const u16* __restrict__ szb,
             const float* __restrict__ carry, u16* __restrict__ ybf) {
  int e = blockIdx.x * 256 + threadIdx.x;
  int b = blockIdx.y;
  int c = blockIdx.z;
  float Ae = -__expf(A_log[e]);
  float De = Dp[e];
  int chain = b * DM + e;
  float h = carry[c * NCHAIN + chain];
  long base = (long)b * LSEQ + (long)c * CL;
  for (int i = 0; i < CL; ++i) {
    long t = base + i;
    float d = delta[t * DM + e];
    float xc = bf2f(xcb[t * DM + e]);
    float Bm = bmc[t * 2];
    float Cc = bmc[t * 2 + 1];
    float a = __expf(d * Ae);
    h = a * h + d * Bm * xc;
    float y = h * Cc + De * xc;
    float sz = bf2f(szb[t * DM + e]);
    ybf[t * DM + e] = f2bf(y * sz);
  }
}

// ---------------- launch ----------------
extern "C" void kernel_launch(void* const* d_in, const int* in_sizes, int n_in,
                              void* d_out, int out_size, void* d_ws, size_t ws_size,
                              hipStream_t stream) {
  const float* x         = (const float*)d_in[0];
  const float* rms_w     = (const float*)d_in[1];
  const float* in_proj_w = (const float*)d_in[2];
  const float* conv_w    = (const float*)d_in[3];
  const float* conv_b    = (const float*)d_in[4];
  const float* x_proj_w  = (const float*)d_in[5];
  const float* dt_proj_w = (const float*)d_in[6];
  const float* dt_proj_b = (const float*)d_in[7];
  const float* A_log     = (const float*)d_in[8];
  const float* Dp        = (const float*)d_in[9];
  const float* out_proj_w= (const float*)d_in[10];
  float* out = (float*)d_out;

  char* ws = (char*)d_ws;
  size_t off = 0;
  auto alloc = [&](size_t bytes) -> void* {
    void* p = ws + off;
    off += (bytes + 255) & ~(size_t)255;
    return p;
  };
  u16*   xnb   = (u16*)alloc((size_t)TOK * DM * 2);
  u16*   xcb   = (u16*)alloc((size_t)TOK * DM * 2);
  u16*   szb   = (u16*)alloc((size_t)TOK * DM * 2);
  u16*   ybf   = (u16*)alloc((size_t)TOK * DM * 2);
  float* bmc   = (float*)alloc((size_t)TOK * 2 * 4);
  float* delta = (float*)alloc((size_t)TOK * DM * 4);
  u16*   wInB  = (u16*)alloc((size_t)1536 * 768 * 2);
  u16*   wDtB  = (u16*)alloc((size_t)768 * 768 * 2);
  u16*   wOutB = (u16*)alloc((size_t)768 * 768 * 2);
  float* aprod = (float*)alloc((size_t)NC * NCHAIN * 4);
  float* hend  = (float*)alloc((size_t)NC * NCHAIN * 4);
  float* carry = (float*)alloc((size_t)NC * NCHAIN * 4);

  cvt_k<<<(1536 * 768 + 255) / 256, 256, 0, stream>>>(in_proj_w, wInB, 1536 * 768);
  cvt_k<<<(768 * 768 + 255) / 256, 256, 0, stream>>>(out_proj_w, wOutB, 768 * 768);
  wdt_k<<<768, 256, 0, stream>>>(dt_proj_w, x_proj_w, wDtB);

  rmsnorm_k<<<TOK, 256, 0, stream>>>(x, rms_w, xnb);

  // xz = xn @ in_proj_w^T ; fused conv+silu -> xcb, silu(z) -> szb
  gemm256<1><<<dim3(1536 / 256, TOK / 256), 512, 0, stream>>>(
      xnb, wInB, nullptr, conv_w, conv_b, xcb, szb);

  // Bm/C via fp32 dots
  bmc_k<<<TOK / 4, 256, 0, stream>>>(xcb, x_proj_w, bmc);

  // delta = softplus(xc @ W_dt^T + dt_b)
  gemm256<2><<<dim3(768 / 256, TOK / 256), 512, 0, stream>>>(
      xcb, wDtB, delta, dt_proj_b, nullptr, nullptr, nullptr);

  scan1_k<<<dim3(3, 8, NC), 256, 0, stream>>>(delta, xcb, bmc, A_log, aprod, hend);
  scan2_k<<<NCHAIN / 256, 256, 0, stream>>>(aprod, hend, carry);
  scan3_k<<<dim3(3, 8, NC), 256, 0, stream>>>(delta, xcb, bmc, A_log, Dp, szb, carry, ybf);

  // out = (y * silu(z)) @ out_proj_w^T
  gemm256<0><<<dim3(768 / 256, TOK / 256), 512, 0, stream>>>(
      ybf, wOutB, out, nullptr, nullptr, nullptr, nullptr);
}